// Round 1
// baseline (344.398 us; speedup 1.0000x reference)
//
#include <hip/hip_runtime.h>
#include <hip/hip_bf16.h>
#include <math.h>

#define NH 1024
#define SEQ 1024
#define BATCH 2
#define NHEAD 16
#define DHEAD 64

// ---------------- Kernel 1: LayerNorm per row ----------------
__global__ __launch_bounds__(256) void k_ln(const float* __restrict__ x,
                                            const float* __restrict__ g,
                                            const float* __restrict__ b,
                                            float* __restrict__ xn) {
    int row = blockIdx.x;
    int t = threadIdx.x;
    const float4* xr = (const float4*)(x + (size_t)row * NH);
    float4 xv = xr[t];
    float s  = xv.x + xv.y + xv.z + xv.w;
    float ss = xv.x*xv.x + xv.y*xv.y + xv.z*xv.z + xv.w*xv.w;
    for (int off = 32; off > 0; off >>= 1) {
        s  += __shfl_down(s, off);
        ss += __shfl_down(ss, off);
    }
    __shared__ float ls[4], lss[4];
    int wid = t >> 6;
    if ((t & 63) == 0) { ls[wid] = s; lss[wid] = ss; }
    __syncthreads();
    s  = ls[0] + ls[1] + ls[2] + ls[3];
    ss = lss[0] + lss[1] + lss[2] + lss[3];
    float mu  = s * (1.0f / NH);
    float var = ss * (1.0f / NH) - mu * mu;
    float rstd = rsqrtf(var + 1e-5f);
    float4 gv = ((const float4*)g)[t];
    float4 bv = ((const float4*)b)[t];
    float4 o;
    o.x = (xv.x - mu) * rstd * gv.x + bv.x;
    o.y = (xv.y - mu) * rstd * gv.y + bv.y;
    o.z = (xv.z - mu) * rstd * gv.z + bv.z;
    o.w = (xv.w - mu) * rstd * gv.w + bv.w;
    ((float4*)(xn + (size_t)row * NH))[t] = o;
}

// ---------------- Kernel 2: q,k projections (16 scalars per row each) ----------------
__global__ __launch_bounds__(256) void k_qk(const float* __restrict__ xn,
                                            const float* __restrict__ Wq,
                                            const float* __restrict__ bq,
                                            const float* __restrict__ Wk,
                                            const float* __restrict__ bk,
                                            float* __restrict__ q,
                                            float* __restrict__ k) {
    int t = threadIdx.x;
    int wave = t >> 6;
    int lane = t & 63;
    int row = blockIdx.x * 4 + wave;
    int h = lane & 15;
    int g = lane >> 4;
    const float* xr = xn + (size_t)row * NH + g * 256;
    float qa = 0.f, ka = 0.f;
#pragma unroll 4
    for (int d = 0; d < 256; ++d) {
        float xv = xr[d];
        int gd = (g * 256 + d) * 16 + h;
        qa = fmaf(xv, Wq[gd], qa);
        ka = fmaf(xv, Wk[gd], ka);
    }
    qa += __shfl_xor(qa, 16);
    ka += __shfl_xor(ka, 16);
    qa += __shfl_xor(qa, 32);
    ka += __shfl_xor(ka, 32);
    if (g == 0) {
        q[row * 16 + h] = qa + bq[h];
        k[row * 16 + h] = ka + bk[h];
    }
}

// ---------------- Kernel 3: v = xn @ Wv + bv  (2048x1024 @ 1024x1024, f32 tiled) ----------------
__global__ __launch_bounds__(256) void k_vgemm(const float* __restrict__ A,
                                               const float* __restrict__ B,
                                               const float* __restrict__ bias,
                                               float* __restrict__ C) {
    __shared__ float AsT[32][68]; // A tile transposed: [k][m]
    __shared__ float Bs[32][68];  // B tile: [k][n]
    int bx = blockIdx.x & 15;   // n tile (16)
    int by = blockIdx.x >> 4;   // m tile (32)
    int t = threadIdx.x;
    int tx = t & 15, ty = t >> 4;
    int tx4 = tx * 4, ty4 = ty * 4;
    int i0 = by * 64, n0 = bx * 64;
    float acc[4][4] = {};
    for (int k0 = 0; k0 < NH; k0 += 32) {
        // stage A tile 64x32 (transposed into LDS)
#pragma unroll
        for (int r = 0; r < 2; ++r) {
            int idx = t + r * 256;
            int row = idx >> 3, c4 = idx & 7;
            float4 av = *(const float4*)(A + (size_t)(i0 + row) * NH + k0 + c4 * 4);
            AsT[c4 * 4 + 0][row] = av.x;
            AsT[c4 * 4 + 1][row] = av.y;
            AsT[c4 * 4 + 2][row] = av.z;
            AsT[c4 * 4 + 3][row] = av.w;
        }
        // stage B tile 32x64
#pragma unroll
        for (int r = 0; r < 2; ++r) {
            int idx = t + r * 256;
            int row = idx >> 4, c4 = idx & 15;
            *(float4*)&Bs[row][c4 * 4] = *(const float4*)(B + (size_t)(k0 + row) * NH + n0 + c4 * 4);
        }
        __syncthreads();
#pragma unroll
        for (int kk = 0; kk < 32; ++kk) {
            float4 a4 = *(float4*)&AsT[kk][ty4];
            float4 b4 = *(float4*)&Bs[kk][tx4];
            acc[0][0] = fmaf(a4.x, b4.x, acc[0][0]);
            acc[0][1] = fmaf(a4.x, b4.y, acc[0][1]);
            acc[0][2] = fmaf(a4.x, b4.z, acc[0][2]);
            acc[0][3] = fmaf(a4.x, b4.w, acc[0][3]);
            acc[1][0] = fmaf(a4.y, b4.x, acc[1][0]);
            acc[1][1] = fmaf(a4.y, b4.y, acc[1][1]);
            acc[1][2] = fmaf(a4.y, b4.z, acc[1][2]);
            acc[1][3] = fmaf(a4.y, b4.w, acc[1][3]);
            acc[2][0] = fmaf(a4.z, b4.x, acc[2][0]);
            acc[2][1] = fmaf(a4.z, b4.y, acc[2][1]);
            acc[2][2] = fmaf(a4.z, b4.z, acc[2][2]);
            acc[2][3] = fmaf(a4.z, b4.w, acc[2][3]);
            acc[3][0] = fmaf(a4.w, b4.x, acc[3][0]);
            acc[3][1] = fmaf(a4.w, b4.y, acc[3][1]);
            acc[3][2] = fmaf(a4.w, b4.z, acc[3][2]);
            acc[3][3] = fmaf(a4.w, b4.w, acc[3][3]);
        }
        __syncthreads();
    }
    float4 bb = *(const float4*)(bias + n0 + tx4);
#pragma unroll
    for (int r = 0; r < 4; ++r) {
        float4 o;
        o.x = acc[r][0] + bb.x;
        o.y = acc[r][1] + bb.y;
        o.z = acc[r][2] + bb.z;
        o.w = acc[r][3] + bb.w;
        *(float4*)(C + (size_t)(i0 + ty4 + r) * NH + n0 + tx4) = o;
    }
}

// ---------------- Kernel 4: fused scores + scores@v + GELU + residual ----------------
__global__ __launch_bounds__(256) void k_attn(const float* __restrict__ q,
                                              const float* __restrict__ kbuf,
                                              const float* __restrict__ v,
                                              const float* __restrict__ x,
                                              const float* __restrict__ mask,
                                              const float* __restrict__ angle,
                                              const float* __restrict__ zfp,
                                              float* __restrict__ out) {
    int blk = blockIdx.x;
    int qt = blk & 15;
    int h = (blk >> 4) & 15;
    int b = blk >> 8;
    int t = threadIdx.x;

    __shared__ float s_lds[64][65];
    __shared__ float v_lds[64][64];
    __shared__ float k_sm[64];
    __shared__ float q_sm[64];

    float ang = angle[h];
    float ca = cosf(ang), sa = sinf(ang);
    float zf = zfp[0];
    int i0 = qt * 64;

    if (t < 64) q_sm[t] = q[((size_t)b * SEQ + i0 + t) * 16 + h];

    int qi = t >> 2, dg = t & 3;
    float ctx[16] = {};
    const float scale = 0.044194173824159216f; // sqrt(2)/sqrt(1024)

    for (int j0 = 0; j0 < SEQ; j0 += 64) {
        if (t < 64) k_sm[t] = kbuf[((size_t)b * SEQ + j0 + t) * 16 + h];
        // stage v tile 64x64
#pragma unroll
        for (int r = 0; r < 4; ++r) {
            int idx = t + r * 256;
            int row = idx >> 4, c4 = idx & 15;
            *(float4*)&v_lds[row][c4 * 4] =
                *(const float4*)(v + ((size_t)b * SEQ + j0 + row) * NH + h * DHEAD + c4 * 4);
        }
        __syncthreads();
        // phase A: scores 64x64 (16 per thread)
#pragma unroll
        for (int r = 0; r < 16; ++r) {
            int idx = t + r * 256;
            int si = idx >> 6, sj = idx & 63;
            float qv = q_sm[si], kv = k_sm[sj];
            float real = ca * qv - sa * kv;
            float imag = sa * qv + ca * kv;
            float d = real - imag;
            float sig = 1.0f / (1.0f + __expf(-d));
            float comp = imag + d * sig;
            float sp = fmaxf(comp, 0.0f) + log1pf(__expf(-fabsf(comp)));
            sp *= (1.0f - mask[(size_t)b * SEQ + j0 + sj]) * scale;
            s_lds[si][sj] = sp;
        }
        __syncthreads();
        // phase B: ctx[64x64] += scores[64x64] @ v[64x64]
        for (int j = 0; j < 64; ++j) {
            float s = s_lds[qi][j];
            float4 v0 = *(float4*)&v_lds[j][dg * 16 + 0];
            float4 v1 = *(float4*)&v_lds[j][dg * 16 + 4];
            float4 v2 = *(float4*)&v_lds[j][dg * 16 + 8];
            float4 v3 = *(float4*)&v_lds[j][dg * 16 + 12];
            ctx[0]  = fmaf(s, v0.x, ctx[0]);
            ctx[1]  = fmaf(s, v0.y, ctx[1]);
            ctx[2]  = fmaf(s, v0.z, ctx[2]);
            ctx[3]  = fmaf(s, v0.w, ctx[3]);
            ctx[4]  = fmaf(s, v1.x, ctx[4]);
            ctx[5]  = fmaf(s, v1.y, ctx[5]);
            ctx[6]  = fmaf(s, v1.z, ctx[6]);
            ctx[7]  = fmaf(s, v1.w, ctx[7]);
            ctx[8]  = fmaf(s, v2.x, ctx[8]);
            ctx[9]  = fmaf(s, v2.y, ctx[9]);
            ctx[10] = fmaf(s, v2.z, ctx[10]);
            ctx[11] = fmaf(s, v2.w, ctx[11]);
            ctx[12] = fmaf(s, v3.x, ctx[12]);
            ctx[13] = fmaf(s, v3.y, ctx[13]);
            ctx[14] = fmaf(s, v3.z, ctx[14]);
            ctx[15] = fmaf(s, v3.w, ctx[15]);
        }
        __syncthreads();
    }

    // epilogue: gelu(ctx)*zf + x
    size_t base = ((size_t)b * SEQ + i0 + qi) * NH + h * DHEAD + dg * 16;
#pragma unroll
    for (int d4 = 0; d4 < 4; ++d4) {
        float4 xv = *(const float4*)(x + base + d4 * 4);
        float4 o;
        float c0 = ctx[d4 * 4 + 0];
        float c1 = ctx[d4 * 4 + 1];
        float c2 = ctx[d4 * 4 + 2];
        float c3 = ctx[d4 * 4 + 3];
        float g0 = 0.5f * c0 * (1.0f + erff(c0 * 0.70710678118654752f));
        float g1 = 0.5f * c1 * (1.0f + erff(c1 * 0.70710678118654752f));
        float g2 = 0.5f * c2 * (1.0f + erff(c2 * 0.70710678118654752f));
        float g3 = 0.5f * c3 * (1.0f + erff(c3 * 0.70710678118654752f));
        o.x = xv.x + g0 * zf;
        o.y = xv.y + g1 * zf;
        o.z = xv.z + g2 * zf;
        o.w = xv.w + g3 * zf;
        *(float4*)(out + base + d4 * 4) = o;
    }
}

extern "C" void kernel_launch(void* const* d_in, const int* in_sizes, int n_in,
                              void* d_out, int out_size, void* d_ws, size_t ws_size,
                              hipStream_t stream) {
    const float* x      = (const float*)d_in[0];
    const float* mask   = (const float*)d_in[1];
    const float* Wq     = (const float*)d_in[2];
    const float* bq     = (const float*)d_in[3];
    const float* Wk     = (const float*)d_in[4];
    const float* bk     = (const float*)d_in[5];
    const float* Wv     = (const float*)d_in[6];
    const float* bv     = (const float*)d_in[7];
    const float* ln_g   = (const float*)d_in[8];
    const float* ln_b   = (const float*)d_in[9];
    const float* zf     = (const float*)d_in[10];
    const float* angle  = (const float*)d_in[11];
    float* out = (float*)d_out;

    float* ws = (float*)d_ws;
    float* xn = ws;                       // 2048*1024
    float* v  = ws + 2097152;             // 2048*1024
    float* q  = ws + 4194304;             // 2048*16
    float* k  = ws + 4194304 + 32768;     // 2048*16

    k_ln<<<BATCH * SEQ, 256, 0, stream>>>(x, ln_g, ln_b, xn);
    k_qk<<<BATCH * SEQ / 4, 256, 0, stream>>>(xn, Wq, bq, Wk, bk, q, k);
    k_vgemm<<<512, 256, 0, stream>>>(xn, Wv, bv, v);
    k_attn<<<BATCH * NHEAD * (SEQ / 64), 256, 0, stream>>>(q, k, v, x, mask, angle, zf, out);
}

// Round 3
// 136.173 us; speedup vs baseline: 2.5291x; 2.5291x over previous
//
#include <hip/hip_runtime.h>
#include <hip/hip_bf16.h>
#include <math.h>

#define NH 1024
#define SEQ 1024
#define BATCH 2
#define NHEAD 16
#define DHEAD 64

typedef __attribute__((ext_vector_type(8))) short short8;
typedef __attribute__((ext_vector_type(4))) float f32x4;
typedef __attribute__((ext_vector_type(4))) unsigned int uint32x4;

__device__ __forceinline__ unsigned short f2bf(float f) {
    unsigned u = __builtin_bit_cast(unsigned, f);
    unsigned r = 0x7FFFu + ((u >> 16) & 1u);
    u += r;
    return (unsigned short)(u >> 16);
}
__device__ __forceinline__ unsigned pk_bf2(float lo, float hi) {
    return (unsigned)f2bf(lo) | ((unsigned)f2bf(hi) << 16);
}

// ---------------- Kernel 1: LayerNorm per row ----------------
__global__ __launch_bounds__(256) void k_ln(const float* __restrict__ x,
                                            const float* __restrict__ g,
                                            const float* __restrict__ b,
                                            float* __restrict__ xn) {
    int row = blockIdx.x;
    int t = threadIdx.x;
    const float4* xr = (const float4*)(x + (size_t)row * NH);
    float4 xv = xr[t];
    float s  = xv.x + xv.y + xv.z + xv.w;
    float ss = xv.x*xv.x + xv.y*xv.y + xv.z*xv.z + xv.w*xv.w;
    for (int off = 32; off > 0; off >>= 1) {
        s  += __shfl_down(s, off);
        ss += __shfl_down(ss, off);
    }
    __shared__ float ls[4], lss[4];
    int wid = t >> 6;
    if ((t & 63) == 0) { ls[wid] = s; lss[wid] = ss; }
    __syncthreads();
    s  = ls[0] + ls[1] + ls[2] + ls[3];
    ss = lss[0] + lss[1] + lss[2] + lss[3];
    float mu  = s * (1.0f / NH);
    float var = ss * (1.0f / NH) - mu * mu;
    float rstd = rsqrtf(var + 1e-5f);
    float4 gv = ((const float4*)g)[t];
    float4 bv = ((const float4*)b)[t];
    float4 o;
    o.x = (xv.x - mu) * rstd * gv.x + bv.x;
    o.y = (xv.y - mu) * rstd * gv.y + bv.y;
    o.z = (xv.z - mu) * rstd * gv.z + bv.z;
    o.w = (xv.w - mu) * rstd * gv.w + bv.w;
    ((float4*)(xn + (size_t)row * NH))[t] = o;
}

// ---------------- Kernel 2: q,k projections, transposed output [h][row] ----------------
__global__ __launch_bounds__(256) void k_qk(const float* __restrict__ xn,
                                            const float* __restrict__ Wq,
                                            const float* __restrict__ bq,
                                            const float* __restrict__ Wk,
                                            const float* __restrict__ bk,
                                            float* __restrict__ qT,
                                            float* __restrict__ kT) {
    int t = threadIdx.x;
    int wave = t >> 6;
    int lane = t & 63;
    int row = blockIdx.x * 4 + wave;
    int h = lane & 15;
    int g = lane >> 4;
    const float* xr = xn + (size_t)row * NH + g * 256;
    float qa = 0.f, ka = 0.f;
#pragma unroll 4
    for (int d = 0; d < 256; ++d) {
        float xv = xr[d];
        int gd = (g * 256 + d) * 16 + h;
        qa = fmaf(xv, Wq[gd], qa);
        ka = fmaf(xv, Wk[gd], ka);
    }
    qa += __shfl_xor(qa, 16);
    ka += __shfl_xor(ka, 16);
    qa += __shfl_xor(qa, 32);
    ka += __shfl_xor(ka, 32);
    if (g == 0) {
        qT[h * 2048 + row] = qa + bq[h];
        kT[h * 2048 + row] = ka + bk[h];
    }
}

// ---------------- Kernel 3: v = xn @ Wv + bv, writes vt[b][h][d][j] bf16 ----------------
__global__ __launch_bounds__(256) void k_vgemm(const float* __restrict__ A,
                                               const float* __restrict__ B,
                                               const float* __restrict__ bias,
                                               unsigned short* __restrict__ vt) {
    __shared__ float AsT[32][68]; // A tile transposed: [k][m]
    __shared__ float Bs[32][68];  // B tile: [k][n]
    __shared__ unsigned short tsm[64][72];
    int bx = blockIdx.x & 15;   // n tile = head
    int by = blockIdx.x >> 4;   // m tile (32)
    int t = threadIdx.x;
    int tx = t & 15, ty = t >> 4;
    int tx4 = tx * 4, ty4 = ty * 4;
    int i0 = by * 64, n0 = bx * 64;
    float acc[4][4] = {};
    for (int k0 = 0; k0 < NH; k0 += 32) {
#pragma unroll
        for (int r = 0; r < 2; ++r) {
            int idx = t + r * 256;
            int row = idx >> 3, c4 = idx & 7;
            float4 av = *(const float4*)(A + (size_t)(i0 + row) * NH + k0 + c4 * 4);
            AsT[c4 * 4 + 0][row] = av.x;
            AsT[c4 * 4 + 1][row] = av.y;
            AsT[c4 * 4 + 2][row] = av.z;
            AsT[c4 * 4 + 3][row] = av.w;
        }
#pragma unroll
        for (int r = 0; r < 2; ++r) {
            int idx = t + r * 256;
            int row = idx >> 4, c4 = idx & 15;
            *(float4*)&Bs[row][c4 * 4] = *(const float4*)(B + (size_t)(k0 + row) * NH + n0 + c4 * 4);
        }
        __syncthreads();
#pragma unroll
        for (int kk = 0; kk < 32; ++kk) {
            float4 a4 = *(float4*)&AsT[kk][ty4];
            float4 b4 = *(float4*)&Bs[kk][tx4];
            acc[0][0] = fmaf(a4.x, b4.x, acc[0][0]);
            acc[0][1] = fmaf(a4.x, b4.y, acc[0][1]);
            acc[0][2] = fmaf(a4.x, b4.z, acc[0][2]);
            acc[0][3] = fmaf(a4.x, b4.w, acc[0][3]);
            acc[1][0] = fmaf(a4.y, b4.x, acc[1][0]);
            acc[1][1] = fmaf(a4.y, b4.y, acc[1][1]);
            acc[1][2] = fmaf(a4.y, b4.z, acc[1][2]);
            acc[1][3] = fmaf(a4.y, b4.w, acc[1][3]);
            acc[2][0] = fmaf(a4.z, b4.x, acc[2][0]);
            acc[2][1] = fmaf(a4.z, b4.y, acc[2][1]);
            acc[2][2] = fmaf(a4.z, b4.z, acc[2][2]);
            acc[2][3] = fmaf(a4.z, b4.w, acc[2][3]);
            acc[3][0] = fmaf(a4.w, b4.x, acc[3][0]);
            acc[3][1] = fmaf(a4.w, b4.y, acc[3][1]);
            acc[3][2] = fmaf(a4.w, b4.z, acc[3][2]);
            acc[3][3] = fmaf(a4.w, b4.w, acc[3][3]);
        }
        __syncthreads();
    }
    float4 bb = *(const float4*)(bias + n0 + tx4);
    // transpose tile into LDS as bf16: tsm[d_local][j_local]
#pragma unroll
    for (int r = 0; r < 4; ++r) {
        tsm[tx4 + 0][ty4 + r] = f2bf(acc[r][0] + bb.x);
        tsm[tx4 + 1][ty4 + r] = f2bf(acc[r][1] + bb.y);
        tsm[tx4 + 2][ty4 + r] = f2bf(acc[r][2] + bb.z);
        tsm[tx4 + 3][ty4 + r] = f2bf(acc[r][3] + bb.w);
    }
    __syncthreads();
    int b = by >> 4;
    int jcol0 = (by & 15) * 64;
    int d = t >> 2, g4 = t & 3;
    uint32x4 w0 = *(const uint32x4*)&tsm[d][g4 * 16];
    uint32x4 w1 = *(const uint32x4*)&tsm[d][g4 * 16 + 8];
    size_t vbase = ((size_t)((b * 16 + bx) * 64 + d)) * 1024 + jcol0 + g4 * 16;
    *(uint32x4*)(vt + vbase) = w0;
    *(uint32x4*)(vt + vbase + 8) = w1;
}

// ---------------- Kernel 4: fused scores (regs) + MFMA PV + GELU + residual ----------------
__device__ __forceinline__ float score_fn(float d, float im) {
    float e = __expf(-d);
    float sg = __builtin_amdgcn_rcpf(1.0f + e);
    float comp = fmaf(d, sg, im);
    float sp = fmaxf(comp, 0.0f) + __logf(1.0f + __expf(-fabsf(comp)));
    return sp;
}

__global__ __launch_bounds__(256, 4) void k_attn(const float* __restrict__ qT,
                                                 const float* __restrict__ kT,
                                                 const unsigned short* __restrict__ vt,
                                                 const float* __restrict__ x,
                                                 const float* __restrict__ mask,
                                                 const float* __restrict__ angle,
                                                 const float* __restrict__ zfp,
                                                 float* __restrict__ out) {
    int blk = blockIdx.x;
    int i0t = blk & 31;
    int h = (blk >> 5) & 15;
    int b = blk >> 9;
    int t = threadIdx.x;
    int w = t >> 6, lane = t & 63, g = lane >> 4, r = lane & 15;
    int i0 = i0t * 32;

    __shared__ float red[4][32][68];

    float ang = angle[h];
    float cs = cosf(ang), sn = sinf(ang);
    float c1 = cs - sn, c2 = cs + sn;
    const float scale = 0.044194173824159216f; // sqrt(2)/sqrt(1024)
    float zf = zfp[0];

    const float* qcol = qT + h * 2048 + b * 1024;
    const float* kcol = kT + h * 2048 + b * 1024;
    const float* mrow = mask + b * 1024;
    const unsigned short* vhead = vt + ((size_t)(b * 16 + h)) * 64 * 1024;

    float qv0 = qcol[i0 + r];
    float qv1 = qcol[i0 + 16 + r];

    f32x4 acc[2][4];
#pragma unroll
    for (int m = 0; m < 2; ++m)
#pragma unroll
        for (int nb = 0; nb < 4; ++nb)
            acc[m][nb] = (f32x4)(0.0f);

    int jw = w * 256;
#pragma unroll 1
    for (int it = 0; it < 8; ++it) {
        int j = jw + it * 32 + g * 8;
        // B fragments straight from global (L2-resident vt)
        short8 bfr[4];
#pragma unroll
        for (int nb = 0; nb < 4; ++nb)
            bfr[nb] = *(const short8*)(vhead + (size_t)(nb * 16 + r) * 1024 + j);
        float4 ka = *(const float4*)(kcol + j);
        float4 kb = *(const float4*)(kcol + j + 4);
        float4 ma = *(const float4*)(mrow + j);
        float4 mb = *(const float4*)(mrow + j + 4);
        float kk[8] = {ka.x, ka.y, ka.z, ka.w, kb.x, kb.y, kb.z, kb.w};
        float mm[8] = {ma.x, ma.y, ma.z, ma.w, mb.x, mb.y, mb.z, mb.w};

        unsigned a0[4], a1[4];
#pragma unroll
        for (int p = 0; p < 4; ++p) {
            float s[4];
#pragma unroll
            for (int half = 0; half < 2; ++half) {
                int jj = p * 2 + half;
                float kv = kk[jj];
                float fac = (1.0f - mm[jj]) * scale;
                float c2k = c2 * kv, csk = cs * kv;
                float d0 = fmaf(c1, qv0, -c2k);
                float i0v = fmaf(sn, qv0, csk);
                s[half * 1 + 0] = score_fn(d0, i0v) * fac;
                float d1 = fmaf(c1, qv1, -c2k);
                float i1v = fmaf(sn, qv1, csk);
                s[2 + half] = score_fn(d1, i1v) * fac;
            }
            a0[p] = pk_bf2(s[0], s[1]);
            a1[p] = pk_bf2(s[2], s[3]);
        }
        uint32x4 av0 = {a0[0], a0[1], a0[2], a0[3]};
        uint32x4 av1 = {a1[0], a1[1], a1[2], a1[3]};
        short8 af0 = __builtin_bit_cast(short8, av0);
        short8 af1 = __builtin_bit_cast(short8, av1);

#pragma unroll
        for (int nb = 0; nb < 4; ++nb) {
            acc[0][nb] = __builtin_amdgcn_mfma_f32_16x16x32_bf16(af0, bfr[nb], acc[0][nb], 0, 0, 0);
            acc[1][nb] = __builtin_amdgcn_mfma_f32_16x16x32_bf16(af1, bfr[nb], acc[1][nb], 0, 0, 0);
        }
    }

    // dump partial ctx to LDS: D layout row=(lane>>4)*4+reg, col=lane&15
#pragma unroll
    for (int m = 0; m < 2; ++m)
#pragma unroll
        for (int nb = 0; nb < 4; ++nb)
#pragma unroll
            for (int jj = 0; jj < 4; ++jj)
                red[w][m * 16 + g * 4 + jj][nb * 16 + r] = acc[m][nb][jj];
    __syncthreads();

    // reduce 4 wave-partials + GELU + residual
    int i = t >> 3, dc = t & 7;
    float c[8] = {};
#pragma unroll
    for (int wv = 0; wv < 4; ++wv) {
        const float* p = &red[wv][i][dc * 8];
        float4 aa = *(const float4*)p;
        float4 bb = *(const float4*)(p + 4);
        c[0] += aa.x; c[1] += aa.y; c[2] += aa.z; c[3] += aa.w;
        c[4] += bb.x; c[5] += bb.y; c[6] += bb.z; c[7] += bb.w;
    }
    size_t base = ((size_t)(b * 1024 + i0 + i)) * 1024 + h * 64 + dc * 8;
    float4 x0 = *(const float4*)(x + base);
    float4 x1 = *(const float4*)(x + base + 4);
    float o[8];
#pragma unroll
    for (int e = 0; e < 8; ++e) {
        float gl = 0.5f * c[e] * (1.0f + erff(c[e] * 0.70710678118654752f));
        o[e] = gl * zf;
    }
    float4 o0, o1;
    o0.x = x0.x + o[0]; o0.y = x0.y + o[1]; o0.z = x0.z + o[2]; o0.w = x0.w + o[3];
    o1.x = x1.x + o[4]; o1.y = x1.y + o[5]; o1.z = x1.z + o[6]; o1.w = x1.w + o[7];
    *(float4*)(out + base) = o0;
    *(float4*)(out + base + 4) = o1;
}

extern "C" void kernel_launch(void* const* d_in, const int* in_sizes, int n_in,
                              void* d_out, int out_size, void* d_ws, size_t ws_size,
                              hipStream_t stream) {
    const float* x      = (const float*)d_in[0];
    const float* mask   = (const float*)d_in[1];
    const float* Wq     = (const float*)d_in[2];
    const float* bq     = (const float*)d_in[3];
    const float* Wk     = (const float*)d_in[4];
    const float* bk     = (const float*)d_in[5];
    const float* Wv     = (const float*)d_in[6];
    const float* bv     = (const float*)d_in[7];
    const float* ln_g   = (const float*)d_in[8];
    const float* ln_b   = (const float*)d_in[9];
    const float* zf     = (const float*)d_in[10];
    const float* angle  = (const float*)d_in[11];
    float* out = (float*)d_out;

    float* ws = (float*)d_ws;
    float* xn = ws;                                  // 2M f32
    unsigned short* vt = (unsigned short*)(ws + 2097152); // 2M bf16 (4MB)
    float* qT = ws + 2097152 + 1048576;              // 16*2048 f32
    float* kT = qT + 32768;

    k_ln<<<BATCH * SEQ, 256, 0, stream>>>(x, ln_g, ln_b, xn);
    k_qk<<<BATCH * SEQ / 4, 256, 0, stream>>>(xn, Wq, bq, Wk, bk, qT, kT);
    k_vgemm<<<512, 256, 0, stream>>>(xn, Wv, bv, vt);
    k_attn<<<BATCH * NHEAD * (SEQ / 32), 256, 0, stream>>>(qT, kT, vt, x, mask, angle, zf, out);
}

// Round 4
// 74.965 us; speedup vs baseline: 4.5942x; 1.8165x over previous
//
#include <hip/hip_runtime.h>
#include <hip/hip_bf16.h>
#include <math.h>

#define NH 1024
#define SEQ 1024
#define BATCH 2
#define NHEAD 16
#define DHEAD 64

typedef __attribute__((ext_vector_type(8))) short short8;
typedef __attribute__((ext_vector_type(4))) float f32x4;

__device__ __forceinline__ unsigned short f2bf(float f) {
    unsigned u = __builtin_bit_cast(unsigned, f);
    unsigned r = 0x7FFFu + ((u >> 16) & 1u);
    u += r;
    return (unsigned short)(u >> 16);
}
__device__ __forceinline__ unsigned pk_bf2(float lo, float hi) {
    return (unsigned)f2bf(lo) | ((unsigned)f2bf(hi) << 16);
}
__device__ __forceinline__ float bf2f(unsigned short s) {
    unsigned u = ((unsigned)s) << 16;
    return __builtin_bit_cast(float, u);
}

typedef __attribute__((address_space(1))) const unsigned int as1_uint;
typedef __attribute__((address_space(3))) unsigned int as3_uint;
__device__ __forceinline__ void gload16(const void* g, void* l) {
    __builtin_amdgcn_global_load_lds((as1_uint*)g, (as3_uint*)l, 16, 0, 0);
}

// ---------------- Kernel 1: LayerNorm per row -> bf16 xn ----------------
__global__ __launch_bounds__(256) void k_ln(const float* __restrict__ x,
                                            const float* __restrict__ g,
                                            const float* __restrict__ b,
                                            unsigned short* __restrict__ xnb) {
    int row = blockIdx.x;
    int t = threadIdx.x;
    const float4* xr = (const float4*)(x + (size_t)row * NH);
    float4 xv = xr[t];
    float s  = xv.x + xv.y + xv.z + xv.w;
    float ss = xv.x*xv.x + xv.y*xv.y + xv.z*xv.z + xv.w*xv.w;
    for (int off = 32; off > 0; off >>= 1) {
        s  += __shfl_down(s, off);
        ss += __shfl_down(ss, off);
    }
    __shared__ float ls[4], lss[4];
    int wid = t >> 6;
    if ((t & 63) == 0) { ls[wid] = s; lss[wid] = ss; }
    __syncthreads();
    s  = ls[0] + ls[1] + ls[2] + ls[3];
    ss = lss[0] + lss[1] + lss[2] + lss[3];
    float mu  = s * (1.0f / NH);
    float var = ss * (1.0f / NH) - mu * mu;
    float rstd = rsqrtf(var + 1e-5f);
    float4 gv = ((const float4*)g)[t];
    float4 bv = ((const float4*)b)[t];
    float o0 = (xv.x - mu) * rstd * gv.x + bv.x;
    float o1 = (xv.y - mu) * rstd * gv.y + bv.y;
    float o2 = (xv.z - mu) * rstd * gv.z + bv.z;
    float o3 = (xv.w - mu) * rstd * gv.w + bv.w;
    uint2 u;
    u.x = pk_bf2(o0, o1);
    u.y = pk_bf2(o2, o3);
    *(uint2*)(xnb + (size_t)row * NH + t * 4) = u;
}

// ---------------- Kernel 2: Wv transpose + bf16: WvT[n][k] ----------------
__global__ __launch_bounds__(256) void k_wvt(const float* __restrict__ Wv,
                                             unsigned short* __restrict__ WvT) {
    __shared__ float T[64][65];
    int k0 = (blockIdx.x >> 4) * 64, n0 = (blockIdx.x & 15) * 64;
    int t = threadIdx.x;
    int row = t >> 2, c4 = t & 3;
#pragma unroll
    for (int s = 0; s < 4; ++s) {
        float4 v = *(const float4*)(Wv + (size_t)(k0 + row) * NH + n0 + c4 * 16 + s * 4);
        *(float4*)&T[row][c4 * 16 + s * 4] = v;
    }
    __syncthreads();
    unsigned short tmp[16] __attribute__((aligned(16)));
#pragma unroll
    for (int s = 0; s < 16; ++s) tmp[s] = f2bf(T[c4 * 16 + s][row]);
    unsigned short* dst = WvT + (size_t)(n0 + row) * NH + k0 + c4 * 16;
    *(short8*)dst = *(const short8*)&tmp[0];
    *(short8*)(dst + 8) = *(const short8*)&tmp[8];
}

// ---------------- Kernel 3: q,k projections from bf16 xn ----------------
__global__ __launch_bounds__(256) void k_qk(const unsigned short* __restrict__ xnb,
                                            const float* __restrict__ Wq,
                                            const float* __restrict__ bq,
                                            const float* __restrict__ Wk,
                                            const float* __restrict__ bk,
                                            float* __restrict__ qT,
                                            float* __restrict__ kT) {
    int t = threadIdx.x;
    int wave = t >> 6;
    int lane = t & 63;
    int row = blockIdx.x * 4 + wave;
    int h = lane & 15;
    int g = lane >> 4;
    const unsigned* xr2 = (const unsigned*)(xnb + (size_t)row * NH + g * 256);
    float qa = 0.f, ka = 0.f;
#pragma unroll 4
    for (int d2 = 0; d2 < 128; ++d2) {
        unsigned u = xr2[d2];
        float x0 = __builtin_bit_cast(float, u << 16);
        float x1 = __builtin_bit_cast(float, u & 0xFFFF0000u);
        int gd = (g * 256 + d2 * 2) * 16 + h;
        qa = fmaf(x0, Wq[gd], qa);
        ka = fmaf(x0, Wk[gd], ka);
        qa = fmaf(x1, Wq[gd + 16], qa);
        ka = fmaf(x1, Wk[gd + 16], ka);
    }
    qa += __shfl_xor(qa, 16);
    ka += __shfl_xor(ka, 16);
    qa += __shfl_xor(qa, 32);
    ka += __shfl_xor(ka, 32);
    if (g == 0) {
        qT[h * 2048 + row] = qa + bq[h];
        kT[h * 2048 + row] = ka + bk[h];
    }
}

// ---------------- Kernel 4: MFMA GEMM v = xn @ Wv + bv -> vt[b][h][d][j] bf16 ----------------
__global__ __launch_bounds__(256) void k_vmfma(const unsigned short* __restrict__ Abf,
                                               const unsigned short* __restrict__ WvT,
                                               const float* __restrict__ bias,
                                               unsigned short* __restrict__ vt) {
    __shared__ unsigned short lds[2][8192]; // per buf: A 64x64 @0 (4096), B 64x64 @4096
    int t = threadIdx.x, w = t >> 6, lane = t & 63, g = lane >> 4, r = lane & 15;
    int mt = blockIdx.x >> 4, nt_ = blockIdx.x & 15;
    int i0 = mt * 64, n0 = nt_ * 64;

    f32x4 acc[2][2];
#pragma unroll
    for (int a = 0; a < 2; ++a)
#pragma unroll
        for (int c = 0; c < 2; ++c) acc[a][c] = (f32x4)(0.0f);

    auto stage = [&](int buf, int k0) {
#pragma unroll
        for (int i = 0; i < 2; ++i) {
            int o = i * 4096 + w * 1024 + lane * 16; // byte offset in tile
            int rr = o >> 7, cb = o & 127;
            int sc = (cb ^ ((rr & 7) << 4)) >> 1;
            gload16(Abf + (size_t)(i0 + rr) * NH + k0 + sc, &lds[buf][o >> 1]);
        }
#pragma unroll
        for (int i = 0; i < 2; ++i) {
            int o = i * 4096 + w * 1024 + lane * 16;
            int rr = o >> 7, cb = o & 127;
            int sc = (cb ^ ((rr & 7) << 4)) >> 1;
            gload16(WvT + (size_t)(n0 + rr) * NH + k0 + sc, &lds[buf][4096 + (o >> 1)]);
        }
    };

    int mbase = (w >> 1) * 32, nbase = (w & 1) * 32;
    int swz = (r & 7) << 4;

    auto compute = [&](int buf) {
        const unsigned short* As = lds[buf];
        const unsigned short* Bs = lds[buf] + 4096;
#pragma unroll
        for (int ks = 0; ks < 2; ++ks) {
            int kbyte = ks * 64 + g * 16;
            int kb = kbyte ^ swz;
            short8 af[2], bfm[2];
#pragma unroll
            for (int mf = 0; mf < 2; ++mf) {
                int row = mbase + mf * 16 + r;
                af[mf] = *(const short8*)(As + ((row * 128 + kb) >> 1));
            }
#pragma unroll
            for (int nf = 0; nf < 2; ++nf) {
                int rowB = nbase + nf * 16 + r;
                bfm[nf] = *(const short8*)(Bs + ((rowB * 128 + kb) >> 1));
            }
#pragma unroll
            for (int mf = 0; mf < 2; ++mf)
#pragma unroll
                for (int nf = 0; nf < 2; ++nf)
                    acc[mf][nf] = __builtin_amdgcn_mfma_f32_16x16x32_bf16(af[mf], bfm[nf], acc[mf][nf], 0, 0, 0);
        }
    };

    stage(0, 0);
    __syncthreads();
    int cur = 0;
#pragma unroll 1
    for (int kt = 0; kt < 15; ++kt) {
        stage(cur ^ 1, (kt + 1) * 64);
        compute(cur);
        __syncthreads();
        cur ^= 1;
    }
    compute(cur);

    // epilogue: bias, bf16, transpose to vt[b][h][d][j]
    unsigned short (*tsm)[72] = (unsigned short(*)[72])&lds[0][0]; // 64x72 shorts, inside buf0
#pragma unroll
    for (int nf = 0; nf < 2; ++nf) {
        float bv = bias[n0 + nbase + nf * 16 + r];
#pragma unroll
        for (int mf = 0; mf < 2; ++mf)
#pragma unroll
            for (int j = 0; j < 4; ++j)
                tsm[nbase + nf * 16 + r][mbase + mf * 16 + g * 4 + j] = f2bf(acc[mf][nf][j] + bv);
    }
    __syncthreads();
    int b = mt >> 4;
    int jc0 = (mt & 15) * 64;
    int d = t >> 2, jb = (t & 3) * 16;
    unsigned short* dst = vt + ((size_t)((b * 16 + nt_) * 64 + d)) * 1024 + jc0 + jb;
    *(short8*)dst = *(const short8*)&tsm[d][jb];
    *(short8*)(dst + 8) = *(const short8*)&tsm[d][jb + 8];
}

// ---------------- Kernel 5: fused scores (regs) + MFMA PV + GELU + residual ----------------
__device__ __forceinline__ float score_fn(float d, float im) {
    float e = __expf(-d);
    float sg = __builtin_amdgcn_rcpf(1.0f + e);
    float comp = fmaf(d, sg, im);
    float sp = fmaxf(comp, 0.0f) + __logf(1.0f + __expf(-fabsf(comp)));
    return sp;
}

__global__ __launch_bounds__(256, 4) void k_attn(const float* __restrict__ qT,
                                                 const float* __restrict__ kT,
                                                 const unsigned short* __restrict__ vt,
                                                 const float* __restrict__ x,
                                                 const float* __restrict__ mask,
                                                 const float* __restrict__ angle,
                                                 const float* __restrict__ zfp,
                                                 float* __restrict__ out) {
    int blk = blockIdx.x;
    int i0t = blk & 31;
    int h = (blk >> 5) & 15;
    int b = blk >> 9;
    int t = threadIdx.x;
    int w = t >> 6, lane = t & 63, g = lane >> 4, r = lane & 15;
    int i0 = i0t * 32;

    __shared__ float red[4][32][68];

    float ang = angle[h];
    float cs = cosf(ang), sn = sinf(ang);
    float c1 = cs - sn, c2 = cs + sn;
    const float scale = 0.044194173824159216f; // sqrt(2)/sqrt(1024)
    float zf = zfp[0];

    const float* qcol = qT + h * 2048 + b * 1024;
    const float* kcol = kT + h * 2048 + b * 1024;
    const float* mrow = mask + b * 1024;
    const unsigned short* vhead = vt + ((size_t)(b * 16 + h)) * 64 * 1024;

    float qv0 = qcol[i0 + r];
    float qv1 = qcol[i0 + 16 + r];

    f32x4 acc[2][4];
#pragma unroll
    for (int m = 0; m < 2; ++m)
#pragma unroll
        for (int nb = 0; nb < 4; ++nb)
            acc[m][nb] = (f32x4)(0.0f);

    int jw = w * 256;
#pragma unroll 1
    for (int it = 0; it < 8; ++it) {
        int j = jw + it * 32 + g * 8;
        short8 bfr[4];
#pragma unroll
        for (int nb = 0; nb < 4; ++nb)
            bfr[nb] = *(const short8*)(vhead + (size_t)(nb * 16 + r) * 1024 + j);
        float4 ka = *(const float4*)(kcol + j);
        float4 kb = *(const float4*)(kcol + j + 4);
        float4 ma = *(const float4*)(mrow + j);
        float4 mb = *(const float4*)(mrow + j + 4);
        float kk[8] = {ka.x, ka.y, ka.z, ka.w, kb.x, kb.y, kb.z, kb.w};
        float mm[8] = {ma.x, ma.y, ma.z, ma.w, mb.x, mb.y, mb.z, mb.w};

        unsigned a0[4], a1[4];
#pragma unroll
        for (int p = 0; p < 4; ++p) {
            float s[4];
#pragma unroll
            for (int half = 0; half < 2; ++half) {
                int jj = p * 2 + half;
                float kv = kk[jj];
                float fac = (1.0f - mm[jj]) * scale;
                float c2k = c2 * kv, csk = cs * kv;
                float d0 = fmaf(c1, qv0, -c2k);
                float i0v = fmaf(sn, qv0, csk);
                s[half] = score_fn(d0, i0v) * fac;
                float d1 = fmaf(c1, qv1, -c2k);
                float i1v = fmaf(sn, qv1, csk);
                s[2 + half] = score_fn(d1, i1v) * fac;
            }
            a0[p] = pk_bf2(s[0], s[1]);
            a1[p] = pk_bf2(s[2], s[3]);
        }
        unsigned av0[4] = {a0[0], a0[1], a0[2], a0[3]};
        unsigned av1[4] = {a1[0], a1[1], a1[2], a1[3]};
        short8 af0 = *(short8*)av0;
        short8 af1 = *(short8*)av1;

#pragma unroll
        for (int nb = 0; nb < 4; ++nb) {
            acc[0][nb] = __builtin_amdgcn_mfma_f32_16x16x32_bf16(af0, bfr[nb], acc[0][nb], 0, 0, 0);
            acc[1][nb] = __builtin_amdgcn_mfma_f32_16x16x32_bf16(af1, bfr[nb], acc[1][nb], 0, 0, 0);
        }
    }

#pragma unroll
    for (int m = 0; m < 2; ++m)
#pragma unroll
        for (int nb = 0; nb < 4; ++nb)
#pragma unroll
            for (int jj = 0; jj < 4; ++jj)
                red[w][m * 16 + g * 4 + jj][nb * 16 + r] = acc[m][nb][jj];
    __syncthreads();

    int i = t >> 3, dc = t & 7;
    float c[8] = {};
#pragma unroll
    for (int wv = 0; wv < 4; ++wv) {
        const float* p = &red[wv][i][dc * 8];
        float4 aa = *(const float4*)p;
        float4 bb = *(const float4*)(p + 4);
        c[0] += aa.x; c[1] += aa.y; c[2] += aa.z; c[3] += aa.w;
        c[4] += bb.x; c[5] += bb.y; c[6] += bb.z; c[7] += bb.w;
    }
    size_t base = ((size_t)(b * 1024 + i0 + i)) * 1024 + h * 64 + dc * 8;
    float4 x0 = *(const float4*)(x + base);
    float4 x1 = *(const float4*)(x + base + 4);
    float o[8];
#pragma unroll
    for (int e = 0; e < 8; ++e) {
        float gl = 0.5f * c[e] * (1.0f + erff(c[e] * 0.70710678118654752f));
        o[e] = gl * zf;
    }
    float4 o0, o1;
    o0.x = x0.x + o[0]; o0.y = x0.y + o[1]; o0.z = x0.z + o[2]; o0.w = x0.w + o[3];
    o1.x = x1.x + o[4]; o1.y = x1.y + o[5]; o1.z = x1.z + o[6]; o1.w = x1.w + o[7];
    *(float4*)(out + base) = o0;
    *(float4*)(out + base + 4) = o1;
}

extern "C" void kernel_launch(void* const* d_in, const int* in_sizes, int n_in,
                              void* d_out, int out_size, void* d_ws, size_t ws_size,
                              hipStream_t stream) {
    const float* x      = (const float*)d_in[0];
    const float* mask   = (const float*)d_in[1];
    const float* Wq     = (const float*)d_in[2];
    const float* bq     = (const float*)d_in[3];
    const float* Wk     = (const float*)d_in[4];
    const float* bk     = (const float*)d_in[5];
    const float* Wv     = (const float*)d_in[6];
    const float* bv     = (const float*)d_in[7];
    const float* ln_g   = (const float*)d_in[8];
    const float* ln_b   = (const float*)d_in[9];
    const float* zf     = (const float*)d_in[10];
    const float* angle  = (const float*)d_in[11];
    float* out = (float*)d_out;

    unsigned short* xnb = (unsigned short*)d_ws;   // 2M bf16
    unsigned short* vt  = xnb + 2097152;           // 2M bf16
    unsigned short* WvT = vt + 2097152;            // 1M bf16
    float* qT = (float*)(WvT + 1048576);           // 32K f32
    float* kT = qT + 32768;                        // 32K f32

    k_wvt<<<256, 256, 0, stream>>>(Wv, WvT);
    k_ln<<<BATCH * SEQ, 256, 0, stream>>>(x, ln_g, ln_b, xnb);
    k_qk<<<BATCH * SEQ / 4, 256, 0, stream>>>(xnb, Wq, bq, Wk, bk, qT, kT);
    k_vmfma<<<512, 256, 0, stream>>>(xnb, WvT, bv, vt);
    k_attn<<<BATCH * NHEAD * (SEQ / 32), 256, 0, stream>>>(qT, kT, vt, x, mask, angle, zf, out);
}